// Round 2
// baseline (488.022 us; speedup 1.0000x reference)
//
#include <hip/hip_runtime.h>

// Problem constants
#define B_ 4
#define N_ 8192
#define E_ 131072      // 2^17
#define HID_ 128

typedef unsigned short us8 __attribute__((ext_vector_type(8)));
typedef unsigned short us4 __attribute__((ext_vector_type(4)));
typedef unsigned int   ui4 __attribute__((ext_vector_type(4)));
typedef int            i4  __attribute__((ext_vector_type(4)));
typedef __bf16         v8bf __attribute__((ext_vector_type(8)));
typedef float          v4f  __attribute__((ext_vector_type(4)));

#define KEY_INF 0xFF800000u   // sortable-u32 key of +inf

__device__ __forceinline__ float b2f(unsigned short u) {
    return __uint_as_float(((unsigned)u) << 16);
}
__device__ __forceinline__ unsigned short f2b(float f) {
    unsigned x = __float_as_uint(f);
    return (unsigned short)((x + 0x7fffu + ((x >> 16) & 1u)) >> 16);   // RNE
}
// monotonic float -> u32 key (unsigned compare order == float order)
__device__ __forceinline__ unsigned fkey(float f) {
    unsigned b = __float_as_uint(f);
    return (b & 0x80000000u) ? ~b : (b | 0x80000000u);
}
__device__ __forceinline__ float funkey(unsigned k) {
    unsigned b = (k & 0x80000000u) ? (k ^ 0x80000000u) : ~k;
    return __uint_as_float(b);
}

// ---- node features (int32) -> bf16 table (exact: values 0..9) ----------
__global__ void k_prep_x0(const int* __restrict__ nf, unsigned short* __restrict__ x0b) {
    int gid = blockIdx.x * 256 + threadIdx.x;           // 131072 threads, 4 elems each
    i4 v = ((const i4*)nf)[gid];
    us4 o;
    o[0] = f2b((float)v[0]); o[1] = f2b((float)v[1]);
    o[2] = f2b((float)v[2]); o[3] = f2b((float)v[3]);
    ((us4*)x0b)[gid] = o;
}

__global__ void k_zero_cnt(unsigned* __restrict__ cnt) {
    cnt[blockIdx.x * 256 + threadIdx.x] = 0u;           // B*N entries
}

__global__ void k_init_agg(unsigned* __restrict__ agg) {
    ui4 v = {KEY_INF, KEY_INF, KEY_INF, KEY_INF};
    ((ui4*)agg)[blockIdx.x * 256 + threadIdx.x] = v;    // B*N*128/4 vec4s
}

// ---- counting sort of edges by dst (per batch) -------------------------
__global__ void k_hist(const int* __restrict__ ei, unsigned* __restrict__ cnt) {
    int gid = blockIdx.x * 256 + threadIdx.x;           // B*E threads
    int b = gid >> 17, e = gid & (E_ - 1);
    int dst = ei[(b << 18) + E_ + e];
    atomicAdd(&cnt[(b << 13) + dst], 1u);
}

__global__ void k_scan(unsigned* __restrict__ cnt) {    // grid = B blocks; in-place cnt -> write-ptrs
    int b = blockIdx.x;
    __shared__ unsigned ps[256];
    unsigned* c = cnt + (b << 13) + threadIdx.x * 32;
    unsigned loc[32]; unsigned s = 0;
#pragma unroll
    for (int i = 0; i < 32; i++) { loc[i] = c[i]; s += loc[i]; }
    ps[threadIdx.x] = s;
    __syncthreads();
    for (int off = 1; off < 256; off <<= 1) {
        unsigned v = (threadIdx.x >= (unsigned)off) ? ps[threadIdx.x - off] : 0u;
        __syncthreads();
        ps[threadIdx.x] += v;
        __syncthreads();
    }
    unsigned run = ps[threadIdx.x] - s;                 // exclusive prefix
#pragma unroll
    for (int i = 0; i < 32; i++) { c[i] = run; run += loc[i]; }
}

__global__ void k_scatter(const int* __restrict__ ei, unsigned* __restrict__ wptr,
                          int* __restrict__ perm) {
    int gid = blockIdx.x * 256 + threadIdx.x;           // B*E threads
    int b = gid >> 17, e = gid & (E_ - 1);
    int dst = ei[(b << 18) + E_ + e];
    unsigned pos = atomicAdd(&wptr[(b << 13) + dst], 1u);
    perm[(b << 17) + pos] = e;
}

// ---- weight repack: fp32 W1[cin][128] -> bf16 W1t[128][kpad] (transposed, 0-pad) ----
__global__ void k_repack(const float* __restrict__ w1, const float* __restrict__ w2,
                         unsigned short* __restrict__ w1t, unsigned short* __restrict__ w2t,
                         int cin, int kpad) {
    int gid = blockIdx.x * 256 + threadIdx.x;
    int t1 = 128 * kpad;
    if (gid < t1) {
        int j = gid / kpad, k = gid - j * kpad;
        w1t[gid] = (k < cin) ? f2b(w1[k * 128 + j]) : (unsigned short)0;
    } else {
        int g = gid - t1;
        if (g < 16384) { int j = g >> 7, k = g & 127; w2t[g] = f2b(w2[k * 128 + j]); }
    }
}

// ---- fused EdgeConv: gather -> MFMA MLP -> segmented min -> atomicMin ----
// 256 threads (4 waves), 64 edges/tile, wave w owns output cols [w*32, w*32+32)
template<int FIN, int KPAD, int ASTRIDE>
__global__ __launch_bounds__(256, 2) void k_conv(
    const unsigned short* __restrict__ x,   // [B][N][FIN] bf16
    const int* __restrict__ ei,             // [B][2][E] int32
    const float* __restrict__ eaf,          // [B][E] fp32
    const int* __restrict__ perm,           // [B][E] edge ids sorted by dst
    const unsigned short* __restrict__ w1t, // [128][KPAD] bf16
    const unsigned short* __restrict__ w2t, // [128][128]  bf16
    const float* __restrict__ bias1, const float* __restrict__ bias2,
    unsigned* __restrict__ agg)             // [B][N][128] sortable keys, init KEY_INF
{
    constexpr int KSTEPS = KPAD / 32;
    constexpr int NCHUNK = KPAD / 8;        // 16B chunks per A-row
    constexpr int ABYTES = 64 * ASTRIDE * 2;
    constexpr int KBYTES = 64 * 132 * 4;    // key buffer (reuses A region)
    constexpr int S0 = (ABYTES > KBYTES ? ABYTES : KBYTES);
    __shared__ __align__(16) char smem[S0 + 64 * 136 * 2 + 64 * 4];
    unsigned short* A1 = (unsigned short*)smem;          // [64][ASTRIDE] bf16
    unsigned*       kb = (unsigned*)smem;                // [64][132] keys (after GEMM1)
    unsigned short* Hs = (unsigned short*)(smem + S0);   // [64][136] bf16
    int*          dstl = (int*)(smem + S0 + 64 * 136 * 2);

    const int tid = threadIdx.x;
    const int wave = tid >> 6, lane = tid & 63, lq = lane >> 4, lm = lane & 15;

    // persistent W fragments: B-operand layout B[k][n], n = lane&15, k = quad*8+j
    v8bf w1f[2][KSTEPS], w2f[2][4];
    float b1v[2], b2v[2];
#pragma unroll
    for (int nt = 0; nt < 2; nt++) {
        const int col = wave * 32 + nt * 16 + lm;
#pragma unroll
        for (int ks = 0; ks < KSTEPS; ks++)
            w1f[nt][ks] = *(const v8bf*)&w1t[col * KPAD + ks * 32 + lq * 8];
#pragma unroll
        for (int ks = 0; ks < 4; ks++)
            w2f[nt][ks] = *(const v8bf*)&w2t[col * 128 + ks * 32 + lq * 8];
        b1v[nt] = bias1[col];
        b2v[nt] = bias2[col];
    }

    const int ntiles = B_ * (E_ / 64);
    for (int t = blockIdx.x; t < ntiles; t += gridDim.x) {
        const int b  = t >> 11;             // E/64 = 2048 tiles per batch
        const int e0 = (t & 2047) * 64;

        // ---- gather: A1 row = [x[dst] | x[src] | ea | 0-pad], 4 threads/edge ----
        {
            const int el = tid >> 2, p = tid & 3;
            const int e   = perm[(b << 17) + e0 + el];
            const int src = ei[(b << 18) + e];
            const int dst = ei[(b << 18) + E_ + e];
            if (p == 0) dstl[el] = dst;
            const unsigned short* xd = x + (size_t)(b * N_ + dst) * FIN;
            const unsigned short* xs = x + (size_t)(b * N_ + src) * FIN;
            const unsigned short eav = f2b(eaf[(b << 17) + e]);
#pragma unroll
            for (int i = 0; i < NCHUNK / 4; i++) {
                const int c = p + 4 * i;
                us8 v = {0, 0, 0, 0, 0, 0, 0, 0};
                if (c < FIN / 8)        v = *(const us8*)(xd + c * 8);
                else if (c < FIN / 4)   v = *(const us8*)(xs + (c - FIN / 8) * 8);
                else if (c == FIN / 4)  v[0] = eav;
                *(us8*)&A1[el * ASTRIDE + c * 8] = v;
            }
        }
        __syncthreads();

        // ---- GEMM1: H = leaky(A1 @ W1 + b1), bf16 into Hs ----
#pragma unroll
        for (int mt = 0; mt < 4; mt++) {
            v4f acc0 = {0.f, 0.f, 0.f, 0.f}, acc1 = {0.f, 0.f, 0.f, 0.f};
            const int arow = mt * 16 + lm;
#pragma unroll
            for (int ks = 0; ks < KSTEPS; ks++) {
                v8bf a = *(const v8bf*)&A1[arow * ASTRIDE + ks * 32 + lq * 8];
                acc0 = __builtin_amdgcn_mfma_f32_16x16x32_bf16(a, w1f[0][ks], acc0, 0, 0, 0);
                acc1 = __builtin_amdgcn_mfma_f32_16x16x32_bf16(a, w1f[1][ks], acc1, 0, 0, 0);
            }
#pragma unroll
            for (int nt = 0; nt < 2; nt++) {
                v4f acc = nt ? acc1 : acc0;
                const int col = wave * 32 + nt * 16 + lm;
                const float bb = nt ? b1v[1] : b1v[0];
#pragma unroll
                for (int r = 0; r < 4; r++) {
                    const int row = mt * 16 + lq * 4 + r;   // C/D: row = quad*4+reg
                    float v = acc[r] + bb;
                    v = (v > 0.f) ? v : 0.01f * v;
                    Hs[row * 136 + col] = f2b(v);
                }
            }
        }
        __syncthreads();   // Hs complete; A1 reads done (kb may overwrite A1)

        // ---- GEMM2: M = Hs @ W2 + b2 -> sortable keys in kb ----
#pragma unroll
        for (int mt = 0; mt < 4; mt++) {
            v4f acc0 = {0.f, 0.f, 0.f, 0.f}, acc1 = {0.f, 0.f, 0.f, 0.f};
            const int arow = mt * 16 + lm;
#pragma unroll
            for (int ks = 0; ks < 4; ks++) {
                v8bf a = *(const v8bf*)&Hs[arow * 136 + ks * 32 + lq * 8];
                acc0 = __builtin_amdgcn_mfma_f32_16x16x32_bf16(a, w2f[0][ks], acc0, 0, 0, 0);
                acc1 = __builtin_amdgcn_mfma_f32_16x16x32_bf16(a, w2f[1][ks], acc1, 0, 0, 0);
            }
#pragma unroll
            for (int nt = 0; nt < 2; nt++) {
                v4f acc = nt ? acc1 : acc0;
                const int col = wave * 32 + nt * 16 + lm;
                const float bb = nt ? b2v[1] : b2v[0];
#pragma unroll
                for (int r = 0; r < 4; r++) {
                    const int row = mt * 16 + lq * 4 + r;
                    kb[row * 132 + col] = fkey(acc[r] + bb);
                }
            }
        }
        __syncthreads();

        // ---- segmented min over sorted dst runs, one atomic per run ----
        {
            const int col = tid & 127;
            const int r0 = (tid >> 7) * 32;     // rows [r0, r0+32)
            unsigned cur = kb[r0 * 132 + col];
            int curd = dstl[r0];
            unsigned* aggb = agg + (size_t)(b * N_) * 128 + col;
            for (int i = 1; i < 32; i++) {
                const int rr = r0 + i;
                const int d = dstl[rr];
                const unsigned kv = kb[rr * 132 + col];
                if (d == curd) { cur = (kv < cur) ? kv : cur; }
                else { atomicMin(aggb + curd * 128, cur); cur = kv; curd = d; }
            }
            atomicMin(aggb + curd * 128, cur);
        }
        __syncthreads();   // protect A1/kb/dstl before next gather
    }
}

// ---- finalize layer: x = leaky(unkey(agg)) (empty node -> 0); re-arm agg ----
__global__ void k_fin(unsigned* __restrict__ agg, unsigned short* __restrict__ xcur) {
    int gid = blockIdx.x * 256 + threadIdx.x;    // B*N*128/4
    ui4 k = ((ui4*)agg)[gid];
    us4 o;
#pragma unroll
    for (int i = 0; i < 4; i++) {
        float v = (k[i] == KEY_INF) ? 0.f : funkey(k[i]);
        v = (v > 0.f) ? v : 0.01f * v;
        o[i] = f2b(v);
    }
    ((us4*)xcur)[gid] = o;
    ui4 r = {KEY_INF, KEY_INF, KEY_INF, KEY_INF};
    ((ui4*)agg)[gid] = r;
}

// ---- head: out = softplus([x0 | x3] @ lin_w + lin_b), fp32 out ----
__global__ void k_final(const unsigned short* __restrict__ x0b, const unsigned short* __restrict__ xc,
                        const float* __restrict__ lw, const float* __restrict__ lb,
                        float* __restrict__ out) {
    __shared__ float w[144 * 8];
    __shared__ float bias[8];
    for (int i = threadIdx.x; i < 1152; i += 256) w[i] = lw[i];
    if (threadIdx.x < 8) bias[threadIdx.x] = lb[threadIdx.x];
    __syncthreads();
    const int n = blockIdx.x * 256 + threadIdx.x;        // B*N nodes
    float acc[8];
#pragma unroll
    for (int a = 0; a < 8; a++) acc[a] = bias[a];
    const unsigned short* x0 = x0b + (size_t)n * 16;
#pragma unroll
    for (int f = 0; f < 16; f++) {
        const float xv = b2f(x0[f]);
#pragma unroll
        for (int a = 0; a < 8; a++) acc[a] += xv * w[f * 8 + a];
    }
    const unsigned short* xr = xc + (size_t)n * 128;
    for (int f = 0; f < 128; f++) {
        const float xv = b2f(xr[f]);
#pragma unroll
        for (int a = 0; a < 8; a++) acc[a] += xv * w[(16 + f) * 8 + a];
    }
#pragma unroll
    for (int a = 0; a < 8; a++) {
        const float v = acc[a];
        const float sp = fmaxf(v, 0.f) + log1pf(expf(-fabsf(v)));   // stable softplus
        out[(size_t)n * 8 + a] = sp;
    }
}

extern "C" void kernel_launch(void* const* d_in, const int* in_sizes, int n_in,
                              void* d_out, int out_size, void* d_ws, size_t ws_size,
                              hipStream_t stream) {
    (void)in_sizes; (void)n_in; (void)out_size; (void)ws_size;
    const int* nf  = (const int*)d_in[0];
    const int* ei  = (const int*)d_in[1];
    const float* eaf = (const float*)d_in[2];
    const float* cw1[3] = {(const float*)d_in[3],  (const float*)d_in[7],  (const float*)d_in[11]};
    const float* cb1[3] = {(const float*)d_in[4],  (const float*)d_in[8],  (const float*)d_in[12]};
    const float* cw2[3] = {(const float*)d_in[5],  (const float*)d_in[9],  (const float*)d_in[13]};
    const float* cb2[3] = {(const float*)d_in[6],  (const float*)d_in[10], (const float*)d_in[14]};
    const float* lw = (const float*)d_in[15];
    const float* lb = (const float*)d_in[16];
    float* out = (float*)d_out;

    // workspace carve (all 256B aligned)
    size_t off = 0;
    auto carve = [&](size_t bytes) { void* p = (char*)d_ws + off; off += (bytes + 255) & ~(size_t)255; return p; };
    unsigned short* x0b  = (unsigned short*)carve((size_t)B_ * N_ * 16 * 2);    // 1 MB
    unsigned short* xcur = (unsigned short*)carve((size_t)B_ * N_ * 128 * 2);   // 8 MB
    unsigned*       agg  = (unsigned*)carve((size_t)B_ * N_ * 128 * 4);         // 16.8 MB
    unsigned*       cnt  = (unsigned*)carve((size_t)B_ * N_ * 4);               // 128 KB (hist -> wptr)
    int*            perm = (int*)carve((size_t)B_ * E_ * 4);                    // 2 MB
    unsigned short* w1t  = (unsigned short*)carve(128 * 288 * 2);
    unsigned short* w2t  = (unsigned short*)carve(128 * 128 * 2);

    k_prep_x0<<<512, 256, 0, stream>>>(nf, x0b);
    k_zero_cnt<<<128, 256, 0, stream>>>(cnt);
    k_init_agg<<<4096, 256, 0, stream>>>(agg);
    k_hist<<<2048, 256, 0, stream>>>(ei, cnt);
    k_scan<<<B_, 256, 0, stream>>>(cnt);
    k_scatter<<<2048, 256, 0, stream>>>(ei, cnt, perm);

    // conv1: FIN=16, cat=33 -> KPAD=64, A-stride 72
    k_repack<<<(128 * 64 + 16384 + 255) / 256, 256, 0, stream>>>(cw1[0], cw2[0], w1t, w2t, 33, 64);
    k_conv<16, 64, 72><<<1024, 256, 0, stream>>>(x0b, ei, eaf, perm, w1t, w2t, cb1[0], cb2[0], agg);
    k_fin<<<4096, 256, 0, stream>>>(agg, xcur);

    // conv2: FIN=128, cat=257 -> KPAD=288, A-stride 296
    k_repack<<<(128 * 288 + 16384 + 255) / 256, 256, 0, stream>>>(cw1[1], cw2[1], w1t, w2t, 257, 288);
    k_conv<128, 288, 296><<<1024, 256, 0, stream>>>(xcur, ei, eaf, perm, w1t, w2t, cb1[1], cb2[1], agg);
    k_fin<<<4096, 256, 0, stream>>>(agg, xcur);

    // conv3
    k_repack<<<(128 * 288 + 16384 + 255) / 256, 256, 0, stream>>>(cw1[2], cw2[2], w1t, w2t, 257, 288);
    k_conv<128, 288, 296><<<1024, 256, 0, stream>>>(xcur, ei, eaf, perm, w1t, w2t, cb1[2], cb2[2], agg);
    k_fin<<<4096, 256, 0, stream>>>(agg, xcur);

    k_final<<<128, 256, 0, stream>>>(x0b, xcur, lw, lb, out);
}

// Round 3
// 393.432 us; speedup vs baseline: 1.2404x; 1.2404x over previous
//
#include <hip/hip_runtime.h>

// Problem constants
#define B_ 4
#define N_ 8192
#define E_ 131072      // 2^17
#define HID_ 128

typedef unsigned short us8 __attribute__((ext_vector_type(8)));
typedef unsigned short us4 __attribute__((ext_vector_type(4)));
typedef unsigned int   ui4 __attribute__((ext_vector_type(4)));
typedef int            i4  __attribute__((ext_vector_type(4)));
typedef __bf16         v8bf __attribute__((ext_vector_type(8)));
typedef float          v4f  __attribute__((ext_vector_type(4)));

#define KEY_INF 0xFF800000u   // sortable-u32 key of +inf

__device__ __forceinline__ float b2f(unsigned short u) {
    return __uint_as_float(((unsigned)u) << 16);
}
__device__ __forceinline__ unsigned short f2b(float f) {
    unsigned x = __float_as_uint(f);
    return (unsigned short)((x + 0x7fffu + ((x >> 16) & 1u)) >> 16);   // RNE
}
// monotonic float -> u32 key (unsigned compare order == float order)
__device__ __forceinline__ unsigned fkey(float f) {
    unsigned b = __float_as_uint(f);
    return (b & 0x80000000u) ? ~b : (b | 0x80000000u);
}
__device__ __forceinline__ float funkey(unsigned k) {
    unsigned b = (k & 0x80000000u) ? (k ^ 0x80000000u) : ~k;
    return __uint_as_float(b);
}

// ---- node features (int32) -> bf16 table (exact: values 0..9) ----------
__global__ void k_prep_x0(const int* __restrict__ nf, unsigned short* __restrict__ x0b) {
    int gid = blockIdx.x * 256 + threadIdx.x;           // 131072 threads, 4 elems each
    i4 v = ((const i4*)nf)[gid];
    us4 o;
    o[0] = f2b((float)v[0]); o[1] = f2b((float)v[1]);
    o[2] = f2b((float)v[2]); o[3] = f2b((float)v[3]);
    ((us4*)x0b)[gid] = o;
}

__global__ void k_zero_cnt(unsigned* __restrict__ cnt) {
    cnt[blockIdx.x * 256 + threadIdx.x] = 0u;           // B*N entries
}

__global__ void k_init_agg(unsigned* __restrict__ agg) {
    ui4 v = {KEY_INF, KEY_INF, KEY_INF, KEY_INF};
    ((ui4*)agg)[blockIdx.x * 256 + threadIdx.x] = v;    // B*N*128/4 vec4s
}

// ---- counting sort of edges by dst (per batch) -------------------------
__global__ void k_hist(const int* __restrict__ ei, unsigned* __restrict__ cnt) {
    int gid = blockIdx.x * 256 + threadIdx.x;           // B*E threads
    int b = gid >> 17, e = gid & (E_ - 1);
    int dst = ei[(b << 18) + E_ + e];
    atomicAdd(&cnt[(b << 13) + dst], 1u);
}

__global__ void k_scan(unsigned* __restrict__ cnt) {    // grid = B blocks; in-place cnt -> write-ptrs
    int b = blockIdx.x;
    __shared__ unsigned ps[256];
    unsigned* c = cnt + (b << 13) + threadIdx.x * 32;
    unsigned loc[32]; unsigned s = 0;
#pragma unroll
    for (int i = 0; i < 32; i++) { loc[i] = c[i]; s += loc[i]; }
    ps[threadIdx.x] = s;
    __syncthreads();
    for (int off = 1; off < 256; off <<= 1) {
        unsigned v = (threadIdx.x >= (unsigned)off) ? ps[threadIdx.x - off] : 0u;
        __syncthreads();
        ps[threadIdx.x] += v;
        __syncthreads();
    }
    unsigned run = ps[threadIdx.x] - s;                 // exclusive prefix
#pragma unroll
    for (int i = 0; i < 32; i++) { c[i] = run; run += loc[i]; }
}

__global__ void k_scatter(const int* __restrict__ ei, unsigned* __restrict__ wptr,
                          int* __restrict__ perm) {
    int gid = blockIdx.x * 256 + threadIdx.x;           // B*E threads
    int b = gid >> 17, e = gid & (E_ - 1);
    int dst = ei[(b << 18) + E_ + e];
    unsigned pos = atomicAdd(&wptr[(b << 13) + dst], 1u);
    perm[(b << 17) + pos] = e;
}

// ---- weight repack: fp32 W1[2F+1][128] -> bf16 W1t[128][KPAD] (transposed, ea row excluded) ----
__global__ void k_repack(const float* __restrict__ w1, const float* __restrict__ w2,
                         unsigned short* __restrict__ w1t, unsigned short* __restrict__ w2t,
                         int kpad) {
    int gid = blockIdx.x * 256 + threadIdx.x;
    int t1 = 128 * kpad;
    if (gid < t1) {
        int j = gid / kpad, k = gid - j * kpad;         // k < kpad = 2F <= cin-1
        w1t[gid] = f2b(w1[k * 128 + j]);
    } else {
        int g = gid - t1;
        if (g < 16384) { int j = g >> 7, k = g & 127; w2t[g] = f2b(w2[k * 128 + j]); }
    }
}

// ---- fused EdgeConv: gather -> MFMA MLP -> register segmented min -> atomicMin ----
// 256 threads (4 waves), 64 edges/tile, wave w owns output cols [w*32, w*32+32).
// A-rows are bit-permuted (swap [5:4]<->[3:2]) so a lane's 16 C-rows are 16
// consecutive dst-sorted edges -> segmented min runs in registers.
template<int FIN, int KPAD, int ASTRIDE, int MINB>
__global__ __launch_bounds__(256, MINB) void k_conv(
    const unsigned short* __restrict__ x,   // [B][N][FIN] bf16
    const int* __restrict__ ei,             // [B][2][E] int32
    const float* __restrict__ eaf,          // [B][E] fp32
    const int* __restrict__ perm,           // [B][E] edge ids sorted by dst
    const unsigned short* __restrict__ w1t, // [128][KPAD] bf16 (rows 0..2F-1)
    const unsigned short* __restrict__ w2t, // [128][128]  bf16
    const float* __restrict__ w1raw,        // [2F+1][128] fp32 (for ea row 2F)
    const float* __restrict__ bias1, const float* __restrict__ bias2,
    unsigned* __restrict__ agg)             // [B][N][128] sortable keys, init KEY_INF
{
    constexpr int KSTEPS = KPAD / 32;
    constexpr int CH = KPAD / 8;            // 16B chunks per A-row (= 2F elems / 8)
    __shared__ __align__(16) unsigned short A1[64 * ASTRIDE];
    __shared__ __align__(16) unsigned short Hs[64 * 136];
    __shared__ __align__(16) int   dstl[64];   // indexed by sorted-edge order
    __shared__ __align__(16) float eal[64];    // indexed by sorted-edge order

    const int tid = threadIdx.x;
    const int wave = tid >> 6, lane = tid & 63, lq = lane >> 4, lm = lane & 15;

    // persistent W fragments: B-operand layout B[k][n], n = lane&15, k = quad*8+j
    v8bf w1f[2][KSTEPS], w2f[2][4];
    float b1v[2], b2v[2], wea[2];
#pragma unroll
    for (int nt = 0; nt < 2; nt++) {
        const int col = wave * 32 + nt * 16 + lm;
#pragma unroll
        for (int ks = 0; ks < KSTEPS; ks++)
            w1f[nt][ks] = *(const v8bf*)&w1t[col * KPAD + ks * 32 + lq * 8];
#pragma unroll
        for (int ks = 0; ks < 4; ks++)
            w2f[nt][ks] = *(const v8bf*)&w2t[col * 128 + ks * 32 + lq * 8];
        b1v[nt] = bias1[col];
        b2v[nt] = bias2[col];
        wea[nt] = w1raw[KPAD * 128 + col];   // W1 row 2F (the edge-attr input)
    }

    const int ntiles = B_ * (E_ / 64);
    for (int t = blockIdx.x; t < ntiles; t += gridDim.x) {
        const int b  = t >> 11;             // E/64 = 2048 tiles per batch
        const int e0 = (t & 2047) * 64;

        // ---- gather: A-row arow holds sorted edge rho(arow); 4 threads/edge ----
        {
            const int arow = tid >> 2, p = tid & 3;
            const int els  = ((arow & 0x0C) << 2) | ((arow >> 2) & 0x0C) | (arow & 3);
            const int e   = perm[(b << 17) + e0 + els];
            const int src = ei[(b << 18) + e];
            const int dst = ei[(b << 18) + E_ + e];
            if (p == 0) { dstl[els] = dst; eal[els] = eaf[(b << 17) + e]; }
            const us8* xdv = (const us8*)(x + (size_t)(b * N_ + dst) * FIN);
            const us8* xsv = (const us8*)(x + (size_t)(b * N_ + src) * FIN);
#pragma unroll
            for (int i = 0; i < CH / 4; i++) {
                const int c = p + 4 * i;
                us8 v = (c < FIN / 8) ? xdv[c] : xsv[c - FIN / 8];
                *(us8*)&A1[arow * ASTRIDE + c * 8] = v;
            }
        }
        __syncthreads();

        // ---- GEMM1: H = leaky(A1 @ W1 + b1 + ea*w1_ea), bf16 into Hs ----
#pragma unroll
        for (int mt = 0; mt < 4; mt++) {
            v4f acc0 = {0.f, 0.f, 0.f, 0.f}, acc1 = {0.f, 0.f, 0.f, 0.f};
            const int arow = mt * 16 + lm;
#pragma unroll
            for (int ks = 0; ks < KSTEPS; ks++) {
                v8bf a = *(const v8bf*)&A1[arow * ASTRIDE + ks * 32 + lq * 8];
                acc0 = __builtin_amdgcn_mfma_f32_16x16x32_bf16(a, w1f[0][ks], acc0, 0, 0, 0);
                acc1 = __builtin_amdgcn_mfma_f32_16x16x32_bf16(a, w1f[1][ks], acc1, 0, 0, 0);
            }
            // C-row mt*16+lq*4+r == sorted edge lq*16+mt*4+r
            v4f eav = *(const v4f*)&eal[lq * 16 + mt * 4];
#pragma unroll
            for (int nt = 0; nt < 2; nt++) {
                v4f acc = nt ? acc1 : acc0;
                const int col = wave * 32 + nt * 16 + lm;
                const float bb = nt ? b1v[1] : b1v[0];
                const float we = nt ? wea[1] : wea[0];
#pragma unroll
                for (int r = 0; r < 4; r++) {
                    const int row = mt * 16 + lq * 4 + r;
                    float v = acc[r] + bb + eav[r] * we;
                    v = (v > 0.f) ? v : 0.01f * v;
                    Hs[row * 136 + col] = f2b(v);
                }
            }
        }
        __syncthreads();   // Hs complete before GEMM2 reads

        // ---- GEMM2 (per mt) + register segmented min over sorted edges ----
        {
            const int col0 = wave * 32 + lm, col1 = col0 + 16;
            unsigned* aggb = agg + (size_t)(b * N_) * 128;
            float cur0 = 0.f, cur1 = 0.f; int curd = -1;
#pragma unroll
            for (int mt = 0; mt < 4; mt++) {
                v4f acc0 = {0.f, 0.f, 0.f, 0.f}, acc1 = {0.f, 0.f, 0.f, 0.f};
                const int arow = mt * 16 + lm;
#pragma unroll
                for (int ks = 0; ks < 4; ks++) {
                    v8bf a = *(const v8bf*)&Hs[arow * 136 + ks * 32 + lq * 8];
                    acc0 = __builtin_amdgcn_mfma_f32_16x16x32_bf16(a, w2f[0][ks], acc0, 0, 0, 0);
                    acc1 = __builtin_amdgcn_mfma_f32_16x16x32_bf16(a, w2f[1][ks], acc1, 0, 0, 0);
                }
                i4 dv = *(const i4*)&dstl[lq * 16 + mt * 4];
#pragma unroll
                for (int r = 0; r < 4; r++) {
                    const float v0 = acc0[r] + b2v[0];
                    const float v1 = acc1[r] + b2v[1];
                    const int d = dv[r];
                    if (d != curd) {
                        if (curd >= 0) {
                            atomicMin(aggb + (size_t)curd * 128 + col0, fkey(cur0));
                            atomicMin(aggb + (size_t)curd * 128 + col1, fkey(cur1));
                        }
                        curd = d; cur0 = v0; cur1 = v1;
                    } else {
                        cur0 = fminf(cur0, v0); cur1 = fminf(cur1, v1);
                    }
                }
            }
            atomicMin(aggb + (size_t)curd * 128 + col0, fkey(cur0));
            atomicMin(aggb + (size_t)curd * 128 + col1, fkey(cur1));
        }
        __syncthreads();   // protect A1/Hs/dstl/eal before next tile's gather
    }
}

// ---- finalize layer: x = leaky(unkey(agg)) (empty node -> 0); re-arm agg ----
__global__ void k_fin(unsigned* __restrict__ agg, unsigned short* __restrict__ xcur) {
    int gid = blockIdx.x * 256 + threadIdx.x;    // B*N*128/4
    ui4 k = ((ui4*)agg)[gid];
    us4 o;
#pragma unroll
    for (int i = 0; i < 4; i++) {
        float v = (k[i] == KEY_INF) ? 0.f : funkey(k[i]);
        v = (v > 0.f) ? v : 0.01f * v;
        o[i] = f2b(v);
    }
    ((us4*)xcur)[gid] = o;
    ui4 r = {KEY_INF, KEY_INF, KEY_INF, KEY_INF};
    ((ui4*)agg)[gid] = r;
}

// ---- head: out = softplus([x0 | x3] @ lin_w + lin_b), fp32 out ----
__global__ void k_final(const unsigned short* __restrict__ x0b, const unsigned short* __restrict__ xc,
                        const float* __restrict__ lw, const float* __restrict__ lb,
                        float* __restrict__ out) {
    __shared__ float w[144 * 8];
    __shared__ float bias[8];
    for (int i = threadIdx.x; i < 1152; i += 256) w[i] = lw[i];
    if (threadIdx.x < 8) bias[threadIdx.x] = lb[threadIdx.x];
    __syncthreads();
    const int n = blockIdx.x * 256 + threadIdx.x;        // B*N nodes
    float acc[8];
#pragma unroll
    for (int a = 0; a < 8; a++) acc[a] = bias[a];
    const unsigned short* x0 = x0b + (size_t)n * 16;
#pragma unroll
    for (int f = 0; f < 16; f++) {
        const float xv = b2f(x0[f]);
#pragma unroll
        for (int a = 0; a < 8; a++) acc[a] += xv * w[f * 8 + a];
    }
    const unsigned short* xr = xc + (size_t)n * 128;
    for (int f = 0; f < 128; f++) {
        const float xv = b2f(xr[f]);
#pragma unroll
        for (int a = 0; a < 8; a++) acc[a] += xv * w[(16 + f) * 8 + a];
    }
#pragma unroll
    for (int a = 0; a < 8; a++) {
        const float v = acc[a];
        const float sp = fmaxf(v, 0.f) + log1pf(expf(-fabsf(v)));   // stable softplus
        out[(size_t)n * 8 + a] = sp;
    }
}

extern "C" void kernel_launch(void* const* d_in, const int* in_sizes, int n_in,
                              void* d_out, int out_size, void* d_ws, size_t ws_size,
                              hipStream_t stream) {
    (void)in_sizes; (void)n_in; (void)out_size; (void)ws_size;
    const int* nf  = (const int*)d_in[0];
    const int* ei  = (const int*)d_in[1];
    const float* eaf = (const float*)d_in[2];
    const float* cw1[3] = {(const float*)d_in[3],  (const float*)d_in[7],  (const float*)d_in[11]};
    const float* cb1[3] = {(const float*)d_in[4],  (const float*)d_in[8],  (const float*)d_in[12]};
    const float* cw2[3] = {(const float*)d_in[5],  (const float*)d_in[9],  (const float*)d_in[13]};
    const float* cb2[3] = {(const float*)d_in[6],  (const float*)d_in[10], (const float*)d_in[14]};
    const float* lw = (const float*)d_in[15];
    const float* lb = (const float*)d_in[16];
    float* out = (float*)d_out;

    // workspace carve (all 256B aligned)
    size_t off = 0;
    auto carve = [&](size_t bytes) { void* p = (char*)d_ws + off; off += (bytes + 255) & ~(size_t)255; return p; };
    unsigned short* x0b  = (unsigned short*)carve((size_t)B_ * N_ * 16 * 2);    // 1 MB
    unsigned short* xcur = (unsigned short*)carve((size_t)B_ * N_ * 128 * 2);   // 8 MB
    unsigned*       agg  = (unsigned*)carve((size_t)B_ * N_ * 128 * 4);         // 16.8 MB
    unsigned*       cnt  = (unsigned*)carve((size_t)B_ * N_ * 4);               // 128 KB (hist -> wptr)
    int*            perm = (int*)carve((size_t)B_ * E_ * 4);                    // 2 MB
    unsigned short* w1t  = (unsigned short*)carve(128 * 256 * 2);
    unsigned short* w2t  = (unsigned short*)carve(128 * 128 * 2);

    k_prep_x0<<<512, 256, 0, stream>>>(nf, x0b);
    k_zero_cnt<<<128, 256, 0, stream>>>(cnt);
    k_init_agg<<<4096, 256, 0, stream>>>(agg);
    k_hist<<<2048, 256, 0, stream>>>(ei, cnt);
    k_scan<<<B_, 256, 0, stream>>>(cnt);
    k_scatter<<<2048, 256, 0, stream>>>(ei, cnt, perm);

    // conv1: FIN=16, K = 32 (+ea rank-1), A-stride 40 -> LDS 23 KB, 4 blocks/CU
    k_repack<<<(128 * 32 + 16384 + 255) / 256, 256, 0, stream>>>(cw1[0], cw2[0], w1t, w2t, 32);
    k_conv<16, 32, 40, 4><<<1024, 256, 0, stream>>>(x0b, ei, eaf, perm, w1t, w2t,
                                                    cw1[0], cb1[0], cb2[0], agg);
    k_fin<<<4096, 256, 0, stream>>>(agg, xcur);

    // conv2: FIN=128, K = 256 (+ea rank-1), A-stride 264 -> LDS 51.7 KB, 3 blocks/CU
    k_repack<<<(128 * 256 + 16384 + 255) / 256, 256, 0, stream>>>(cw1[1], cw2[1], w1t, w2t, 256);
    k_conv<128, 256, 264, 3><<<1024, 256, 0, stream>>>(xcur, ei, eaf, perm, w1t, w2t,
                                                       cw1[1], cb1[1], cb2[1], agg);
    k_fin<<<4096, 256, 0, stream>>>(agg, xcur);

    // conv3
    k_repack<<<(128 * 256 + 16384 + 255) / 256, 256, 0, stream>>>(cw1[2], cw2[2], w1t, w2t, 256);
    k_conv<128, 256, 264, 3><<<1024, 256, 0, stream>>>(xcur, ei, eaf, perm, w1t, w2t,
                                                       cw1[2], cb1[2], cb2[2], agg);
    k_fin<<<4096, 256, 0, stream>>>(agg, xcur);

    k_final<<<128, 256, 0, stream>>>(x0b, xcur, lw, lb, out);
}

// Round 4
// 335.608 us; speedup vs baseline: 1.4541x; 1.1723x over previous
//
#include <hip/hip_runtime.h>

// Problem constants
#define B_ 4
#define N_ 8192
#define E_ 131072      // 2^17
#define HID_ 128

typedef unsigned short us8 __attribute__((ext_vector_type(8)));
typedef unsigned short us4 __attribute__((ext_vector_type(4)));
typedef unsigned int   ui4 __attribute__((ext_vector_type(4)));
typedef int            i4  __attribute__((ext_vector_type(4)));
typedef __bf16         v8bf __attribute__((ext_vector_type(8)));
typedef float          v4f  __attribute__((ext_vector_type(4)));

#define KEY_INF 0xFF800000u   // sortable-u32 key of +inf

__device__ __forceinline__ float b2f(unsigned short u) {
    return __uint_as_float(((unsigned)u) << 16);
}
__device__ __forceinline__ unsigned short f2b(float f) {
    unsigned x = __float_as_uint(f);
    return (unsigned short)((x + 0x7fffu + ((x >> 16) & 1u)) >> 16);   // RNE
}
// monotonic float -> u32 key (unsigned compare order == float order)
__device__ __forceinline__ unsigned fkey(float f) {
    unsigned b = __float_as_uint(f);
    return (b & 0x80000000u) ? ~b : (b | 0x80000000u);
}
__device__ __forceinline__ float funkey(unsigned k) {
    unsigned b = (k & 0x80000000u) ? (k ^ 0x80000000u) : ~k;
    return __uint_as_float(b);
}

// ---- node features (int32) -> bf16 table (exact: values 0..9) ----------
__global__ void k_prep_x0(const int* __restrict__ nf, unsigned short* __restrict__ x0b) {
    int gid = blockIdx.x * 256 + threadIdx.x;           // 131072 threads, 4 elems each
    i4 v = ((const i4*)nf)[gid];
    us4 o;
    o[0] = f2b((float)v[0]); o[1] = f2b((float)v[1]);
    o[2] = f2b((float)v[2]); o[3] = f2b((float)v[3]);
    ((us4*)x0b)[gid] = o;
}

__global__ void k_zero_cnt(unsigned* __restrict__ cnt) {
    cnt[blockIdx.x * 256 + threadIdx.x] = 0u;           // B*N entries
}

__global__ void k_init_agg(unsigned* __restrict__ agg) {
    ui4 v = {KEY_INF, KEY_INF, KEY_INF, KEY_INF};
    ((ui4*)agg)[blockIdx.x * 256 + threadIdx.x] = v;    // B*N*128/4 vec4s
}

// ---- counting sort of edges by dst (per batch) -------------------------
__global__ void k_hist(const int* __restrict__ ei, unsigned* __restrict__ cnt) {
    int gid = blockIdx.x * 256 + threadIdx.x;           // B*E threads
    int b = gid >> 17, e = gid & (E_ - 1);
    int dst = ei[(b << 18) + E_ + e];
    atomicAdd(&cnt[(b << 13) + dst], 1u);
}

__global__ void k_scan(unsigned* __restrict__ cnt) {    // grid = B blocks; in-place cnt -> write-ptrs
    int b = blockIdx.x;
    __shared__ unsigned ps[256];
    unsigned* c = cnt + (b << 13) + threadIdx.x * 32;
    unsigned loc[32]; unsigned s = 0;
#pragma unroll
    for (int i = 0; i < 32; i++) { loc[i] = c[i]; s += loc[i]; }
    ps[threadIdx.x] = s;
    __syncthreads();
    for (int off = 1; off < 256; off <<= 1) {
        unsigned v = (threadIdx.x >= (unsigned)off) ? ps[threadIdx.x - off] : 0u;
        __syncthreads();
        ps[threadIdx.x] += v;
        __syncthreads();
    }
    unsigned run = ps[threadIdx.x] - s;                 // exclusive prefix
#pragma unroll
    for (int i = 0; i < 32; i++) { c[i] = run; run += loc[i]; }
}

__global__ void k_scatter(const int* __restrict__ ei, unsigned* __restrict__ wptr,
                          int* __restrict__ perm) {
    int gid = blockIdx.x * 256 + threadIdx.x;           // B*E threads
    int b = gid >> 17, e = gid & (E_ - 1);
    int dst = ei[(b << 18) + E_ + e];
    unsigned pos = atomicAdd(&wptr[(b << 13) + dst], 1u);
    perm[(b << 17) + pos] = e;
}

// ---- weight repack ------------------------------------------------------
// w1n[256 cols][KPAD]: col j<128 -> W1a col j (rows 0..F-1), j>=128 -> W1b col j-128
// w2t[128 cols][128]
__global__ void k_repackN(const float* __restrict__ w1, const float* __restrict__ w2,
                          unsigned short* __restrict__ w1n, unsigned short* __restrict__ w2t,
                          int F, int KPAD) {
    int gid = blockIdx.x * 256 + threadIdx.x;
    int t1 = 256 * KPAD;
    if (gid < t1) {
        int j = gid / KPAD, k = gid - j * KPAD;
        float v = 0.f;
        if (k < F) v = (j < 128) ? w1[k * 128 + j] : w1[(F + k) * 128 + (j - 128)];
        w1n[gid] = f2b(v);
    } else {
        int g = gid - t1;
        if (g < 16384) { int j = g >> 7, k = g & 127; w2t[g] = f2b(w2[k * 128 + j]); }
    }
}

// ---- per-node projection: [Yd|Ys] = x @ [W1a|W1b] (+b1 on Yd half) -----
// 64 node-rows/block, 4 waves x 64 cols. FROM_AGG: x = leaky(unkey(agg)), re-arms agg.
template<int KPAD, bool FROM_AGG>
__global__ __launch_bounds__(256, 3) void k_node(
    const unsigned short* __restrict__ xin,   // x0b (FROM_AGG=false)
    unsigned* __restrict__ agg,               // read + re-arm (FROM_AGG=true)
    const unsigned short* __restrict__ w1n,   // [256][KPAD] bf16
    const float* __restrict__ bias1,
    unsigned short* __restrict__ Yd,          // [B][N][128] bf16
    unsigned short* __restrict__ Ys)          // [B][N][128] bf16
{
    constexpr int ASTR = KPAD + 8;
    __shared__ __align__(16) unsigned short A[64 * ASTR];
    __shared__ __align__(16) unsigned short Yb[64 * 264];

    const int tid = threadIdx.x;
    const int wave = tid >> 6, lane = tid & 63, lq = lane >> 4, lm = lane & 15;
    const int tile = (blockIdx.x & 7) * 64 + (blockIdx.x >> 3);   // XCD-affine
    const int n0 = tile * 64;

    v8bf wf[4][KPAD / 32]; float b1v[4];
#pragma unroll
    for (int nt = 0; nt < 4; nt++) {
        const int col = wave * 64 + nt * 16 + lm;
#pragma unroll
        for (int ks = 0; ks < KPAD / 32; ks++)
            wf[nt][ks] = *(const v8bf*)&w1n[col * KPAD + ks * 32 + lq * 8];
        b1v[nt] = (col < 128) ? bias1[col] : 0.f;
    }

    // stage A (64 rows x KPAD)
    {
        const int row = tid >> 2, p = tid & 3;
        if (FROM_AGG) {
#pragma unroll
            for (int i = 0; i < 8; i++) {
                const int c = p + 4 * i;      // 32 ui4 chunks of 4 cols
                unsigned* ap = agg + ((size_t)(n0 + row)) * 128 + c * 4;
                ui4 k = *(ui4*)ap;
                ui4 inf = {KEY_INF, KEY_INF, KEY_INF, KEY_INF};
                *(ui4*)ap = inf;              // re-arm for next layer's atomics
                us4 o;
#pragma unroll
                for (int j = 0; j < 4; j++) {
                    float v = (k[j] == KEY_INF) ? 0.f : funkey(k[j]);
                    v = (v > 0.f) ? v : 0.01f * v;
                    o[j] = f2b(v);
                }
                *(us4*)&A[row * ASTR + c * 4] = o;
            }
        } else {
            us4 v = *(const us4*)(xin + ((size_t)(n0 + row)) * 16 + p * 4);
            *(us4*)&A[row * ASTR + p * 4] = v;
            us4 z = {0, 0, 0, 0};
            *(us4*)&A[row * ASTR + 16 + p * 4] = z;   // zero-pad K 16->32
        }
    }
    __syncthreads();

#pragma unroll
    for (int mt = 0; mt < 4; mt++) {
        v4f acc[4];
#pragma unroll
        for (int nt = 0; nt < 4; nt++) acc[nt] = v4f{0.f, 0.f, 0.f, 0.f};
#pragma unroll
        for (int ks = 0; ks < KPAD / 32; ks++) {
            v8bf a = *(const v8bf*)&A[(mt * 16 + lm) * ASTR + ks * 32 + lq * 8];
#pragma unroll
            for (int nt = 0; nt < 4; nt++)
                acc[nt] = __builtin_amdgcn_mfma_f32_16x16x32_bf16(a, wf[nt][ks], acc[nt], 0, 0, 0);
        }
#pragma unroll
        for (int nt = 0; nt < 4; nt++) {
            const int col = wave * 64 + nt * 16 + lm;
#pragma unroll
            for (int r = 0; r < 4; r++)
                Yb[(mt * 16 + lq * 4 + r) * 264 + col] = f2b(acc[nt][r] + b1v[nt]);
        }
    }
    __syncthreads();

    // coalesced copy-out
    const int bb = tile >> 7, nl0 = (tile & 127) * 64;
#pragma unroll
    for (int i = 0; i < 8; i++) {
        const int idx = tid + 256 * i;          // 2048 us8 chunks
        const int row = idx >> 5, c = idx & 31;
        us8 v = *(const us8*)&Yb[row * 264 + c * 8];
        const int col0 = c * 8;
        unsigned short* dp = (col0 < 128)
            ? (Yd + ((size_t)(bb * N_) + nl0 + row) * 128 + col0)
            : (Ys + ((size_t)(bb * N_) + nl0 + row) * 128 + (col0 - 128));
        *(us8*)dp = v;
    }
}

// ---- fused edge kernel: gather Yd[dst]+Ys[src]+ea*wea -> leaky -> Hs ----
// -> GEMM2 (persistent W2 frags) -> register segmented min -> atomicMin.
// 128 edges/tile, 4 tiles/block, XCD-affine windows. A-rows permuted so a
// lane's 32 C-rows are 32 consecutive dst-sorted edges.
__global__ __launch_bounds__(256, 4) void k_edge(
    const unsigned short* __restrict__ Yd,
    const unsigned short* __restrict__ Ys,
    const int* __restrict__ ei,
    const float* __restrict__ eaf,
    const int* __restrict__ perm,
    const unsigned short* __restrict__ w2t,   // [128][128] bf16
    const float* __restrict__ weap,           // [128] = W1 row 2F (edge-attr)
    const float* __restrict__ bias2,
    unsigned* __restrict__ agg)
{
    __shared__ __align__(16) unsigned short Hs[128 * 136];
    __shared__ __align__(16) int   dstl[128];   // indexed by sorted order s
    __shared__ __align__(16) float weal[128];

    const int tid = threadIdx.x;
    const int wave = tid >> 6, lane = tid & 63, lq = lane >> 4, lm = lane & 15;

    if (tid < 128) weal[tid] = weap[tid];

    v8bf w2f[2][4]; float b2v[2];
#pragma unroll
    for (int nt = 0; nt < 2; nt++) {
        const int col = wave * 32 + nt * 16 + lm;
#pragma unroll
        for (int ks = 0; ks < 4; ks++)
            w2f[nt][ks] = *(const v8bf*)&w2t[col * 128 + ks * 32 + lq * 8];
        b2v[nt] = bias2[col];
    }
    __syncthreads();   // weal visible

    // gather role: 2 threads/edge; arow = Hs row; s = sorted-edge index
    const int arow = tid >> 1, p = tid & 1;
    const int s = ((arow & 0x70) >> 2) | ((arow & 0x0C) << 3) | (arow & 3);

    // prefetch tile 0 indices (3-level pointer chase hidden behind GEMM2 later)
    int t = (blockIdx.x & 7) * 512 + (blockIdx.x >> 3);   // XCD window
    int b = t >> 10;
    int e = perm[(b << 17) + (t & 1023) * 128 + s];
    int src = ei[(b << 18) + e];
    int dst = ei[(b << 18) + E_ + e];
    float ea = eaf[(b << 17) + e];

    for (int jj = 0; jj < 4; jj++) {
        const int curb = b, curdst = dst, cursrc = src;
        const float curea = ea;
        if (p == 0) dstl[s] = curdst;
        const unsigned short* ydp = Yd + ((size_t)(curb * N_) + curdst) * 128;
        const unsigned short* ysp = Ys + ((size_t)(curb * N_) + cursrc) * 128;
#pragma unroll
        for (int i = 0; i < 8; i++) {
            const int c = p + 2 * i;
            us8 va = *(const us8*)(ydp + c * 8);
            us8 vb = *(const us8*)(ysp + c * 8);
            us8 o;
#pragma unroll
            for (int j = 0; j < 8; j++) {
                float v = b2f(va[j]) + b2f(vb[j]) + curea * weal[c * 8 + j];
                v = (v > 0.f) ? v : 0.01f * v;
                o[j] = f2b(v);
            }
            *(us8*)&Hs[arow * 136 + c * 8] = o;
        }
        __syncthreads();

        // prefetch next tile's indices (registers only; no LDS hazard)
        t += 128;
        if (jj < 3) {
            b = t >> 10;
            e = perm[(b << 17) + (t & 1023) * 128 + s];
            src = ei[(b << 18) + e];
            dst = ei[(b << 18) + E_ + e];
            ea = eaf[(b << 17) + e];
        }

        // GEMM2 + register segmented min over sorted edges
        {
            const int col0 = wave * 32 + lm, col1 = col0 + 16;
            unsigned* aggb = agg + (size_t)(curb * N_) * 128;
            float cur0 = 0.f, cur1 = 0.f; int curd = -1;
#pragma unroll
            for (int mt = 0; mt < 8; mt++) {
                v4f acc0 = {0.f, 0.f, 0.f, 0.f}, acc1 = {0.f, 0.f, 0.f, 0.f};
#pragma unroll
                for (int ks = 0; ks < 4; ks++) {
                    v8bf a = *(const v8bf*)&Hs[(mt * 16 + lm) * 136 + ks * 32 + lq * 8];
                    acc0 = __builtin_amdgcn_mfma_f32_16x16x32_bf16(a, w2f[0][ks], acc0, 0, 0, 0);
                    acc1 = __builtin_amdgcn_mfma_f32_16x16x32_bf16(a, w2f[1][ks], acc1, 0, 0, 0);
                }
                i4 dv = *(const i4*)&dstl[lq * 32 + mt * 4];
#pragma unroll
                for (int r = 0; r < 4; r++) {
                    const float v0 = acc0[r] + b2v[0];
                    const float v1 = acc1[r] + b2v[1];
                    const int d = dv[r];
                    if (d != curd) {
                        if (curd >= 0) {
                            atomicMin(aggb + (size_t)curd * 128 + col0, fkey(cur0));
                            atomicMin(aggb + (size_t)curd * 128 + col1, fkey(cur1));
                        }
                        curd = d; cur0 = v0; cur1 = v1;
                    } else {
                        cur0 = fminf(cur0, v0); cur1 = fminf(cur1, v1);
                    }
                }
            }
            atomicMin(aggb + (size_t)curd * 128 + col0, fkey(cur0));
            atomicMin(aggb + (size_t)curd * 128 + col1, fkey(cur1));
        }
        __syncthreads();   // protect Hs/dstl before next tile's gather
    }
}

// ---- head: out = softplus([x0 | leaky(unkey(agg))] @ lin_w + lin_b) ----
__global__ void k_final(const unsigned short* __restrict__ x0b, const unsigned* __restrict__ agg,
                        const float* __restrict__ lw, const float* __restrict__ lb,
                        float* __restrict__ out) {
    __shared__ float w[144 * 8];
    __shared__ float bias[8];
    for (int i = threadIdx.x; i < 1152; i += 256) w[i] = lw[i];
    if (threadIdx.x < 8) bias[threadIdx.x] = lb[threadIdx.x];
    __syncthreads();
    const int n = blockIdx.x * 256 + threadIdx.x;        // B*N nodes
    float acc[8];
#pragma unroll
    for (int a = 0; a < 8; a++) acc[a] = bias[a];
    const unsigned short* x0 = x0b + (size_t)n * 16;
#pragma unroll
    for (int f = 0; f < 16; f++) {
        const float xv = b2f(x0[f]);
#pragma unroll
        for (int a = 0; a < 8; a++) acc[a] += xv * w[f * 8 + a];
    }
    const unsigned* ar = agg + (size_t)n * 128;
    for (int f = 0; f < 128; f++) {
        const unsigned k = ar[f];
        float xv = (k == KEY_INF) ? 0.f : funkey(k);
        xv = (xv > 0.f) ? xv : 0.01f * xv;
#pragma unroll
        for (int a = 0; a < 8; a++) acc[a] += xv * w[(16 + f) * 8 + a];
    }
#pragma unroll
    for (int a = 0; a < 8; a++) {
        const float v = acc[a];
        const float sp = fmaxf(v, 0.f) + log1pf(expf(-fabsf(v)));   // stable softplus
        out[(size_t)n * 8 + a] = sp;
    }
}

extern "C" void kernel_launch(void* const* d_in, const int* in_sizes, int n_in,
                              void* d_out, int out_size, void* d_ws, size_t ws_size,
                              hipStream_t stream) {
    (void)in_sizes; (void)n_in; (void)out_size; (void)ws_size;
    const int* nf  = (const int*)d_in[0];
    const int* ei  = (const int*)d_in[1];
    const float* eaf = (const float*)d_in[2];
    const float* cw1[3] = {(const float*)d_in[3],  (const float*)d_in[7],  (const float*)d_in[11]};
    const float* cb1[3] = {(const float*)d_in[4],  (const float*)d_in[8],  (const float*)d_in[12]};
    const float* cw2[3] = {(const float*)d_in[5],  (const float*)d_in[9],  (const float*)d_in[13]};
    const float* cb2[3] = {(const float*)d_in[6],  (const float*)d_in[10], (const float*)d_in[14]};
    const float* lw = (const float*)d_in[15];
    const float* lb = (const float*)d_in[16];
    float* out = (float*)d_out;

    // workspace carve (all 256B aligned) — ~36.9 MB total
    size_t off = 0;
    auto carve = [&](size_t bytes) { void* p = (char*)d_ws + off; off += (bytes + 255) & ~(size_t)255; return p; };
    unsigned short* x0b  = (unsigned short*)carve((size_t)B_ * N_ * 16 * 2);    // 1 MB
    unsigned*       agg  = (unsigned*)carve((size_t)B_ * N_ * 128 * 4);         // 16.8 MB
    unsigned*       cnt  = (unsigned*)carve((size_t)B_ * N_ * 4);               // 128 KB
    int*            perm = (int*)carve((size_t)B_ * E_ * 4);                    // 2 MB
    unsigned short* Yd   = (unsigned short*)carve((size_t)B_ * N_ * 128 * 2);   // 8.4 MB
    unsigned short* Ys   = (unsigned short*)carve((size_t)B_ * N_ * 128 * 2);   // 8.4 MB
    unsigned short* w1n  = (unsigned short*)carve(256 * 128 * 2);
    unsigned short* w2t  = (unsigned short*)carve(128 * 128 * 2);

    k_prep_x0<<<512, 256, 0, stream>>>(nf, x0b);
    k_zero_cnt<<<128, 256, 0, stream>>>(cnt);
    k_init_agg<<<4096, 256, 0, stream>>>(agg);
    k_hist<<<2048, 256, 0, stream>>>(ei, cnt);
    k_scan<<<B_, 256, 0, stream>>>(cnt);
    k_scatter<<<2048, 256, 0, stream>>>(ei, cnt, perm);

    // conv1: F=16 (KPAD 32)
    k_repackN<<<96, 256, 0, stream>>>(cw1[0], cw2[0], w1n, w2t, 16, 32);
    k_node<32, false><<<512, 256, 0, stream>>>(x0b, agg, w1n, cb1[0], Yd, Ys);
    k_edge<<<1024, 256, 0, stream>>>(Yd, Ys, ei, eaf, perm, w2t, cw1[0] + 32 * 128, cb2[0], agg);

    // conv2: F=128 (KPAD 128); k_node reads conv1 agg + re-arms it
    k_repackN<<<192, 256, 0, stream>>>(cw1[1], cw2[1], w1n, w2t, 128, 128);
    k_node<128, true><<<512, 256, 0, stream>>>(x0b, agg, w1n, cb1[1], Yd, Ys);
    k_edge<<<1024, 256, 0, stream>>>(Yd, Ys, ei, eaf, perm, w2t, cw1[1] + 256 * 128, cb2[1], agg);

    // conv3
    k_repackN<<<192, 256, 0, stream>>>(cw1[2], cw2[2], w1n, w2t, 128, 128);
    k_node<128, true><<<512, 256, 0, stream>>>(x0b, agg, w1n, cb1[2], Yd, Ys);
    k_edge<<<1024, 256, 0, stream>>>(Yd, Ys, ei, eaf, perm, w2t, cw1[2] + 256 * 128, cb2[2], agg);

    k_final<<<128, 256, 0, stream>>>(x0b, agg, lw, lb, out);
}